// Round 3
// baseline (436.327 us; speedup 1.0000x reference)
//
#include <hip/hip_runtime.h>
#include <hip/hip_bf16.h>

// STDP collapses to: dw = scale * (A^T @ P),  A=neurotransmitters (B=256,S=8192),
// P=action_potential (B=256,T=8192), scale=(0.05*0.05-0.01*0.05)*0.001/256.
// neuromodulators and synaptic_weights are never read.
//
// R5: conservative re-expression of the R3 pipeline after two container
// failures — the m248-verified "minimum 2-phase" schedule with ONLY standard
// HIP semantics (no inline asm, no raw s_barrier):
//   stage(next) -> compute(cur) -> __syncthreads()
// The vmcnt(0) drain inside __syncthreads happens AFTER compute, so next-tile
// loads hide under the MFMA phase. Double-buffered LDS (64 KB, 2 blocks/CU),
// XCD-aware bijective block swizzle (4096 wgs, 512/XCD), nontemporal C stores
// (C streams 256 MiB through L2 once; 8 MB At/Pt stay resident), vectorized cvt.

typedef __bf16 bf16x8 __attribute__((ext_vector_type(8)));
typedef __bf16 bf16x4 __attribute__((ext_vector_type(4)));
typedef float f32x4 __attribute__((ext_vector_type(4)));

#define S_DIM 8192
#define T_DIM 8192
#define K_DIM 256
#define BK 64

__device__ inline void async_load16(const void* g, void* lds) {
  __builtin_amdgcn_global_load_lds(
      (const __attribute__((address_space(1))) void*)g,
      (__attribute__((address_space(3))) void*)lds, 16, 0, 0);
}

// z=0: in0 (K x S) fp32 -> out0 (S x K) bf16;  z=1: in1 -> out1 (T x K)
__global__ __launch_bounds__(256) void cvt_transpose2(const float* __restrict__ in0,
                                                      const float* __restrict__ in1,
                                                      __bf16* __restrict__ out0,
                                                      __bf16* __restrict__ out1) {
  const float* in = blockIdx.z ? in1 : in0;
  __bf16* out = blockIdx.z ? out1 : out0;
  __shared__ float tile[32][33];
  const int t = threadIdx.x;
  const int s0 = blockIdx.x * 32, k0 = blockIdx.y * 32;
  {
    const int kl = t >> 3;            // 0..31 row (k)
    const int s4 = (t & 7) * 4;       // 0..28 col (s), float4
    const float4 v = *(const float4*)(in + (size_t)(k0 + kl) * S_DIM + s0 + s4);
    tile[kl][s4 + 0] = v.x;
    tile[kl][s4 + 1] = v.y;
    tile[kl][s4 + 2] = v.z;
    tile[kl][s4 + 3] = v.w;
  }
  __syncthreads();
  {
    const int sl = t >> 3;            // 0..31 row (s)
    const int k4 = (t & 7) * 4;       // 0..28 col (k), bf16x4
    bf16x4 o;
    o[0] = (__bf16)tile[k4 + 0][sl];
    o[1] = (__bf16)tile[k4 + 1][sl];
    o[2] = (__bf16)tile[k4 + 2][sl];
    o[3] = (__bf16)tile[k4 + 3][sl];
    *(bf16x4*)(out + (size_t)(s0 + sl) * K_DIM + k0 + k4) = o;
  }
}

// At: (S x K) bf16, Pt: (T x K) bf16, C: (S x T) fp32
__global__ __launch_bounds__(256, 2) void stdp_gemm(const __bf16* __restrict__ At,
                                                    const __bf16* __restrict__ Pt,
                                                    float* __restrict__ C,
                                                    float scale) {
  __shared__ __attribute__((aligned(16))) __bf16 As[2][128 * BK];
  __shared__ __attribute__((aligned(16))) __bf16 Bs[2][128 * BK];

  const int tid = threadIdx.x;
  const int wave = tid >> 6;
  const int lane = tid & 63;
  const int quad = lane >> 4;       // 0..3
  const int l16 = lane & 15;        // 0..15
  const int wm = (wave >> 1) * 64;  // wave row offset in 128x128 tile
  const int wn = (wave & 1) * 64;   // wave col offset

  // XCD-aware chunked swizzle: 4096 wgs (divisible by 8), 512 contiguous/XCD.
  const int id = blockIdx.y * gridDim.x + blockIdx.x;
  const int swz = (id & 7) * 512 + (id >> 3);
  const int m0 = (swz >> 6) * 128;  // 64 tiles per row
  const int n0 = (swz & 63) * 128;

  // staging decomposition: one issue = 64 lanes = 8 rows x 8 chunks of 16B.
  // lane L -> row rbase + (L>>3), LDS slot (L&7); global chunk = slot ^ (row&7).
  const int srow = lane >> 3;
  const int schunk = (lane & 7) ^ srow;

  const size_t ga = (size_t)(m0 + srow) * K_DIM + schunk * 8;
  const size_t gb = (size_t)(n0 + srow) * K_DIM + schunk * 8;

  f32x4 acc[4][4] = {};

  // each wave stages 32 rows of A and 32 rows of B: 8 load_lds issues / tile
  auto stage = [&](int buf, int kk) {
#pragma unroll
    for (int i = 0; i < 4; ++i) {
      const int rbase = wave * 32 + i * 8;  // wave-uniform
      async_load16(At + ga + (size_t)rbase * K_DIM + kk, &As[buf][rbase * BK]);
      async_load16(Pt + gb + (size_t)rbase * K_DIM + kk, &Bs[buf][rbase * BK]);
    }
  };

  stage(0, 0);
  __syncthreads();  // tile 0 ready (only fully-exposed load latency)

#pragma unroll
  for (int it = 0; it < 4; ++it) {
    const int cb = it & 1;
    if (it < 3) stage(cb ^ 1, (it + 1) * BK);  // issue next tile; lands during MFMA

#pragma unroll
    for (int ks = 0; ks < 2; ++ks) {  // two k-steps of 32 within BK=64
      bf16x8 af[4], bfr[4];
#pragma unroll
      for (int i = 0; i < 4; ++i) {
        const int row = wm + i * 16 + l16;
        const int c = (ks * 4 + quad) ^ (row & 7);  // swizzled slot
        af[i] = *(const bf16x8*)(&As[cb][row * BK + c * 8]);
      }
#pragma unroll
      for (int j = 0; j < 4; ++j) {
        const int row = wn + j * 16 + l16;
        const int c = (ks * 4 + quad) ^ (row & 7);
        bfr[j] = *(const bf16x8*)(&Bs[cb][row * BK + c * 8]);
      }
#pragma unroll
      for (int i = 0; i < 4; ++i)
#pragma unroll
        for (int j = 0; j < 4; ++j)
          acc[i][j] = __builtin_amdgcn_mfma_f32_16x16x32_bf16(af[i], bfr[j], acc[i][j], 0, 0, 0);
    }

    if (it < 3) __syncthreads();  // drains next-tile loads + read-done; after
                                  // compute, so the vmcnt(0) cost is residual
  }

  // epilogue: C/D layout col=lane&15, row=quad*4+reg (m89/m91-verified)
#pragma unroll
  for (int i = 0; i < 4; ++i) {
    const int mrow = m0 + wm + i * 16 + quad * 4;
#pragma unroll
    for (int j = 0; j < 4; ++j) {
      const int ncol = n0 + wn + j * 16 + l16;
      float* outp = C + (size_t)mrow * T_DIM + ncol;
#pragma unroll
      for (int r = 0; r < 4; ++r)
        __builtin_nontemporal_store(acc[i][j][r] * scale, outp + (size_t)r * T_DIM);
    }
  }
}

extern "C" void kernel_launch(void* const* d_in, const int* in_sizes, int n_in,
                              void* d_out, int out_size, void* d_ws, size_t ws_size,
                              hipStream_t stream) {
  const float* pre = (const float*)d_in[0];   // neurotransmitters (B,S)
  const float* post = (const float*)d_in[2];  // action_potential (B,T)
  float* out = (float*)d_out;

  __bf16* At = (__bf16*)d_ws;                 // (S, K) bf16: 4 MB
  __bf16* Pt = At + (size_t)S_DIM * K_DIM;    // (T, K) bf16: 4 MB

  const float scale = (float)((0.05 * 0.05 - 0.01 * 0.05) * 0.001 / 256.0);

  cvt_transpose2<<<dim3(S_DIM / 32, K_DIM / 32, 2), dim3(256), 0, stream>>>(pre, post, At, Pt);
  stdp_gemm<<<dim3(T_DIM / 128, S_DIM / 128), 256, 0, stream>>>(At, Pt, out, scale);
}

// Round 4
// 406.108 us; speedup vs baseline: 1.0744x; 1.0744x over previous
//
#include <hip/hip_runtime.h>
#include <hip/hip_bf16.h>

// STDP collapses to: dw = scale * (A^T @ P),  A=neurotransmitters (B=256,S=8192),
// P=action_potential (B=256,T=8192), scale=(0.05*0.05-0.01*0.05)*0.001/256.
// neuromodulators and synaptic_weights are never read.
//
// R6: un-bundling R5's regression (436 vs 405 baseline). Keep ONLY the
// 2-phase double-buffered schedule (stage(next) -> compute(cur) -> one
// __syncthreads per iter; next-tile global_load_lds lands under the MFMA
// phase, so the barrier's vmcnt(0) drain cost is residual). Reverted vs R5:
//   - no nontemporal stores (suspect: nt bypasses L2 write-combining of the
//     64B store segments -> worse HBM efficiency on the dominant 256 MiB
//     C-write stream)
//   - no __launch_bounds__ min-waves arg (suspect: 128-VGPR cap -> spills;
//     acc 64 + frags 32 + addressing ~= 130)
//   - no XCD swizzle (inputs are L2/L3-resident; swizzle is noise-to-negative
//     when cache-fit)
// Standard HIP sync only — the R3/R4 inline-asm+raw-barrier version killed
// the container twice (likely wave hang).

typedef __bf16 bf16x8 __attribute__((ext_vector_type(8)));
typedef __bf16 bf16x4 __attribute__((ext_vector_type(4)));
typedef float f32x4 __attribute__((ext_vector_type(4)));

#define S_DIM 8192
#define T_DIM 8192
#define K_DIM 256
#define BK 64

__device__ inline void async_load16(const void* g, void* lds) {
  __builtin_amdgcn_global_load_lds(
      (const __attribute__((address_space(1))) void*)g,
      (__attribute__((address_space(3))) void*)lds, 16, 0, 0);
}

// z=0: in0 (K x S) fp32 -> out0 (S x K) bf16;  z=1: in1 -> out1 (T x K)
__global__ __launch_bounds__(256) void cvt_transpose2(const float* __restrict__ in0,
                                                      const float* __restrict__ in1,
                                                      __bf16* __restrict__ out0,
                                                      __bf16* __restrict__ out1) {
  const float* in = blockIdx.z ? in1 : in0;
  __bf16* out = blockIdx.z ? out1 : out0;
  __shared__ float tile[32][33];
  const int t = threadIdx.x;
  const int s0 = blockIdx.x * 32, k0 = blockIdx.y * 32;
  {
    const int kl = t >> 3;            // 0..31 row (k)
    const int s4 = (t & 7) * 4;       // 0..28 col (s), float4
    const float4 v = *(const float4*)(in + (size_t)(k0 + kl) * S_DIM + s0 + s4);
    tile[kl][s4 + 0] = v.x;
    tile[kl][s4 + 1] = v.y;
    tile[kl][s4 + 2] = v.z;
    tile[kl][s4 + 3] = v.w;
  }
  __syncthreads();
  {
    const int sl = t >> 3;            // 0..31 row (s)
    const int k4 = (t & 7) * 4;       // 0..28 col (k), bf16x4
    bf16x4 o;
    o[0] = (__bf16)tile[k4 + 0][sl];
    o[1] = (__bf16)tile[k4 + 1][sl];
    o[2] = (__bf16)tile[k4 + 2][sl];
    o[3] = (__bf16)tile[k4 + 3][sl];
    *(bf16x4*)(out + (size_t)(s0 + sl) * K_DIM + k0 + k4) = o;
  }
}

// At: (S x K) bf16, Pt: (T x K) bf16, C: (S x T) fp32
__global__ __launch_bounds__(256) void stdp_gemm(const __bf16* __restrict__ At,
                                                 const __bf16* __restrict__ Pt,
                                                 float* __restrict__ C,
                                                 float scale) {
  __shared__ __attribute__((aligned(16))) __bf16 As[2][128 * BK];
  __shared__ __attribute__((aligned(16))) __bf16 Bs[2][128 * BK];

  const int tid = threadIdx.x;
  const int wave = tid >> 6;
  const int lane = tid & 63;
  const int quad = lane >> 4;       // 0..3
  const int l16 = lane & 15;        // 0..15
  const int wm = (wave >> 1) * 64;  // wave row offset in 128x128 tile
  const int wn = (wave & 1) * 64;   // wave col offset
  const int m0 = blockIdx.y * 128;
  const int n0 = blockIdx.x * 128;

  // staging decomposition: one issue = 64 lanes = 8 rows x 8 chunks of 16B.
  // lane L -> row rbase + (L>>3), LDS slot (L&7); global chunk = slot ^ (row&7).
  const int srow = lane >> 3;
  const int schunk = (lane & 7) ^ srow;

  const size_t ga = (size_t)(m0 + srow) * K_DIM + schunk * 8;
  const size_t gb = (size_t)(n0 + srow) * K_DIM + schunk * 8;

  f32x4 acc[4][4] = {};

  // each wave stages 32 rows of A and 32 rows of B: 8 load_lds issues / tile
  auto stage = [&](int buf, int kk) {
#pragma unroll
    for (int i = 0; i < 4; ++i) {
      const int rbase = wave * 32 + i * 8;  // wave-uniform
      async_load16(At + ga + (size_t)rbase * K_DIM + kk, &As[buf][rbase * BK]);
      async_load16(Pt + gb + (size_t)rbase * K_DIM + kk, &Bs[buf][rbase * BK]);
    }
  };

  stage(0, 0);
  __syncthreads();  // tile 0 ready (only fully-exposed load latency)

#pragma unroll
  for (int it = 0; it < 4; ++it) {
    const int cb = it & 1;
    if (it < 3) stage(cb ^ 1, (it + 1) * BK);  // issue next tile; lands during MFMA

#pragma unroll
    for (int ks = 0; ks < 2; ++ks) {  // two k-steps of 32 within BK=64
      bf16x8 af[4], bfr[4];
#pragma unroll
      for (int i = 0; i < 4; ++i) {
        const int row = wm + i * 16 + l16;
        const int c = (ks * 4 + quad) ^ (row & 7);  // swizzled slot
        af[i] = *(const bf16x8*)(&As[cb][row * BK + c * 8]);
      }
#pragma unroll
      for (int j = 0; j < 4; ++j) {
        const int row = wn + j * 16 + l16;
        const int c = (ks * 4 + quad) ^ (row & 7);
        bfr[j] = *(const bf16x8*)(&Bs[cb][row * BK + c * 8]);
      }
#pragma unroll
      for (int i = 0; i < 4; ++i)
#pragma unroll
        for (int j = 0; j < 4; ++j)
          acc[i][j] = __builtin_amdgcn_mfma_f32_16x16x32_bf16(af[i], bfr[j], acc[i][j], 0, 0, 0);
    }

    if (it < 3) __syncthreads();  // drains next-tile loads + read-done; after
                                  // compute, so the vmcnt(0) cost is residual
  }

  // epilogue: C/D layout col=lane&15, row=quad*4+reg (m89/m91-verified)
#pragma unroll
  for (int i = 0; i < 4; ++i) {
    const int mrow = m0 + wm + i * 16 + quad * 4;
#pragma unroll
    for (int j = 0; j < 4; ++j) {
      const int ncol = n0 + wn + j * 16 + l16;
      float* outp = C + (size_t)mrow * T_DIM + ncol;
#pragma unroll
      for (int r = 0; r < 4; ++r)
        outp[(size_t)r * T_DIM] = acc[i][j][r] * scale;
    }
  }
}

extern "C" void kernel_launch(void* const* d_in, const int* in_sizes, int n_in,
                              void* d_out, int out_size, void* d_ws, size_t ws_size,
                              hipStream_t stream) {
  const float* pre = (const float*)d_in[0];   // neurotransmitters (B,S)
  const float* post = (const float*)d_in[2];  // action_potential (B,T)
  float* out = (float*)d_out;

  __bf16* At = (__bf16*)d_ws;                 // (S, K) bf16: 4 MB
  __bf16* Pt = At + (size_t)S_DIM * K_DIM;    // (T, K) bf16: 4 MB

  const float scale = (float)((0.05 * 0.05 - 0.01 * 0.05) * 0.001 / 256.0);

  cvt_transpose2<<<dim3(S_DIM / 32, K_DIM / 32, 2), dim3(256), 0, stream>>>(pre, post, At, Pt);
  stdp_gemm<<<dim3(T_DIM / 128, S_DIM / 128), 256, 0, stream>>>(At, Pt, out, scale);
}